// Round 1
// baseline (596.600 us; speedup 1.0000x reference)
//
#include <hip/hip_runtime.h>

#define BETA1 0.9f
#define BETA2 0.99f
#define ADAM_EPS 1e-8f

// Pure elementwise Adam (MetaSGD variant with per-element learnable lr).
// Memory-bound: 20 B read + 4 B write per element. float4-vectorized,
// grid-stride, single kernel over all three concatenated tensors.
__global__ __launch_bounds__(256) void metasgd_adam_kernel(
    const float4* __restrict__ w0, const float4* __restrict__ g0,
    const float4* __restrict__ l0, const float4* __restrict__ m0,
    const float4* __restrict__ v0,
    const float4* __restrict__ w1, const float4* __restrict__ g1,
    const float4* __restrict__ l1, const float4* __restrict__ m1,
    const float4* __restrict__ v1,
    const float4* __restrict__ w2, const float4* __restrict__ g2,
    const float4* __restrict__ l2, const float4* __restrict__ m2,
    const float4* __restrict__ v2,
    const int* __restrict__ step_ptr,
    float4* __restrict__ out,
    unsigned n0v, unsigned n1v, unsigned n2v)   // vec4 counts per tensor
{
    const int s = *step_ptr;  // L2-cached scalar; same for all threads
    const float bc1 = 1.0f - powf(BETA1, (float)s);
    const float bc2 = 1.0f - powf(BETA2, (float)s);
    const float inv_bc1 = 1.0f / bc1;
    const float inv_sqrt_bc2 = rsqrtf(bc2);

    const unsigned total = n0v + n1v + n2v;
    const unsigned stride = gridDim.x * blockDim.x;

    for (unsigned i = blockIdx.x * blockDim.x + threadIdx.x; i < total;
         i += stride) {
        const float4 *W, *G, *L, *M, *V;
        unsigned j;
        if (i < n0v) {
            W = w0; G = g0; L = l0; M = m0; V = v0; j = i;
        } else if (i < n0v + n1v) {
            W = w1; G = g1; L = l1; M = m1; V = v1; j = i - n0v;
        } else {
            W = w2; G = g2; L = l2; M = m2; V = v2; j = i - n0v - n1v;
        }

        const float4 w = W[j];
        const float4 g = G[j];
        const float4 lr = L[j];
        const float4 m = M[j];
        const float4 v = V[j];
        float4 o;

#define ADAM_LANE(c)                                                      \
        {                                                                 \
            const float mn = BETA1 * m.c + (1.0f - BETA1) * g.c;          \
            const float vn = BETA2 * v.c + (1.0f - BETA2) * g.c * g.c;    \
            const float denom = sqrtf(vn) * inv_sqrt_bc2 + ADAM_EPS;      \
            o.c = w.c - (lr.c * inv_bc1) * mn / denom;                    \
        }
        ADAM_LANE(x)
        ADAM_LANE(y)
        ADAM_LANE(z)
        ADAM_LANE(w)
#undef ADAM_LANE

        out[i] = o;
    }
}

extern "C" void kernel_launch(void* const* d_in, const int* in_sizes, int n_in,
                              void* d_out, int out_size, void* d_ws, size_t ws_size,
                              hipStream_t stream) {
    // Input order: w0,g0,lr0,m0,v0, w1,g1,lr1,m1,v1, w2,g2,lr2,m2,v2, step
    const float4* w0 = (const float4*)d_in[0];
    const float4* g0 = (const float4*)d_in[1];
    const float4* l0 = (const float4*)d_in[2];
    const float4* m0 = (const float4*)d_in[3];
    const float4* v0 = (const float4*)d_in[4];
    const float4* w1 = (const float4*)d_in[5];
    const float4* g1 = (const float4*)d_in[6];
    const float4* l1 = (const float4*)d_in[7];
    const float4* m1 = (const float4*)d_in[8];
    const float4* v1 = (const float4*)d_in[9];
    const float4* w2 = (const float4*)d_in[10];
    const float4* g2 = (const float4*)d_in[11];
    const float4* l2 = (const float4*)d_in[12];
    const float4* m2 = (const float4*)d_in[13];
    const float4* v2 = (const float4*)d_in[14];
    const int* step  = (const int*)d_in[15];

    // All three sizes are divisible by 4 (16777216, 16777216, 8192).
    const unsigned n0v = (unsigned)in_sizes[0] / 4;
    const unsigned n1v = (unsigned)in_sizes[5] / 4;
    const unsigned n2v = (unsigned)in_sizes[10] / 4;
    const unsigned total = n0v + n1v + n2v;

    const int block = 256;
    // Memory-bound: cap grid at ~8 blocks/CU x 256 CUs, grid-stride the rest.
    unsigned grid = (total + block - 1) / block;
    if (grid > 2048) grid = 2048;

    metasgd_adam_kernel<<<grid, block, 0, stream>>>(
        w0, g0, l0, m0, v0,
        w1, g1, l1, m1, v1,
        w2, g2, l2, m2, v2,
        step, (float4*)d_out, n0v, n1v, n2v);
}

// Round 2
// 582.258 us; speedup vs baseline: 1.0246x; 1.0246x over previous
//
#include <hip/hip_runtime.h>

#define BETA1 0.9f
#define BETA2 0.99f
#define ADAM_EPS 1e-8f

// Elementwise Adam (MetaSGD, per-element lr). Memory-bound: 20 B read +
// 4 B write per element. One float4 per thread, exact-size grid.
// Tensor select is by blockIdx range -> wave-uniform branch, SGPR pointers.
__global__ __launch_bounds__(256) void metasgd_adam_kernel(
    const float4* __restrict__ w0, const float4* __restrict__ g0,
    const float4* __restrict__ l0, const float4* __restrict__ m0,
    const float4* __restrict__ v0,
    const float4* __restrict__ w1, const float4* __restrict__ g1,
    const float4* __restrict__ l1, const float4* __restrict__ m1,
    const float4* __restrict__ v1,
    const float4* __restrict__ w2, const float4* __restrict__ g2,
    const float4* __restrict__ l2, const float4* __restrict__ m2,
    const float4* __restrict__ v2,
    const int* __restrict__ step_ptr,
    float4* __restrict__ out,
    unsigned n0v, unsigned n1v, unsigned n2v,   // vec4 counts per tensor
    unsigned blk1, unsigned blk2)               // first block of tensor1 / tensor2
{
    const unsigned b = blockIdx.x;

    // Wave-uniform (blockIdx-based) tensor select -> scalar pointers.
    const float4 *W, *G, *L, *M, *V;
    float4* O;
    unsigned nv, local_base;
    if (b < blk1) {
        W = w0; G = g0; L = l0; M = m0; V = v0;
        O = out;               nv = n0v; local_base = b * 256u;
    } else if (b < blk2) {
        W = w1; G = g1; L = l1; M = m1; V = v1;
        O = out + n0v;         nv = n1v; local_base = (b - blk1) * 256u;
    } else {
        W = w2; G = g2; L = l2; M = m2; V = v2;
        O = out + n0v + n1v;   nv = n2v; local_base = (b - blk2) * 256u;
    }

    const unsigned j = local_base + threadIdx.x;
    if (j >= nv) return;

    const int s = *step_ptr;
    const float bc1 = 1.0f - powf(BETA1, (float)s);
    const float bc2 = 1.0f - powf(BETA2, (float)s);
    const float inv_bc1 = 1.0f / bc1;
    const float inv_sqrt_bc2 = rsqrtf(bc2);

    const float4 w = W[j];
    const float4 g = G[j];
    const float4 lr = L[j];
    const float4 m = M[j];
    const float4 v = V[j];
    float4 o;

#define ADAM_LANE(c)                                                        \
    {                                                                       \
        const float mn = fmaf(BETA1, m.c, (1.0f - BETA1) * g.c);            \
        const float vn = fmaf(BETA2, v.c, (1.0f - BETA2) * (g.c * g.c));    \
        const float denom = fmaf(sqrtf(vn), inv_sqrt_bc2, ADAM_EPS);        \
        const float r = __builtin_amdgcn_rcpf(denom);                       \
        o.c = fmaf(-(lr.c * inv_bc1) * mn, r, w.c);                         \
    }
    ADAM_LANE(x)
    ADAM_LANE(y)
    ADAM_LANE(z)
    ADAM_LANE(w)
#undef ADAM_LANE

    O[j] = o;
}

extern "C" void kernel_launch(void* const* d_in, const int* in_sizes, int n_in,
                              void* d_out, int out_size, void* d_ws, size_t ws_size,
                              hipStream_t stream) {
    // Input order: w0,g0,lr0,m0,v0, w1,g1,lr1,m1,v1, w2,g2,lr2,m2,v2, step
    const float4* w0 = (const float4*)d_in[0];
    const float4* g0 = (const float4*)d_in[1];
    const float4* l0 = (const float4*)d_in[2];
    const float4* m0 = (const float4*)d_in[3];
    const float4* v0 = (const float4*)d_in[4];
    const float4* w1 = (const float4*)d_in[5];
    const float4* g1 = (const float4*)d_in[6];
    const float4* l1 = (const float4*)d_in[7];
    const float4* m1 = (const float4*)d_in[8];
    const float4* v1 = (const float4*)d_in[9];
    const float4* w2 = (const float4*)d_in[10];
    const float4* g2 = (const float4*)d_in[11];
    const float4* l2 = (const float4*)d_in[12];
    const float4* m2 = (const float4*)d_in[13];
    const float4* v2 = (const float4*)d_in[14];
    const int* step  = (const int*)d_in[15];

    // All sizes divisible by 4 (16777216, 16777216, 8192).
    const unsigned n0v = (unsigned)in_sizes[0] / 4;
    const unsigned n1v = (unsigned)in_sizes[5] / 4;
    const unsigned n2v = (unsigned)in_sizes[10] / 4;

    const unsigned blk0 = (n0v + 255u) / 256u;   // 16384
    const unsigned blk1 = (n1v + 255u) / 256u;   // 16384
    const unsigned blk2 = (n2v + 255u) / 256u;   // 8
    const unsigned grid = blk0 + blk1 + blk2;    // 32776

    metasgd_adam_kernel<<<grid, 256, 0, stream>>>(
        w0, g0, l0, m0, v0,
        w1, g1, l1, m1, v1,
        w2, g2, l2, m2, v2,
        step, (float4*)d_out, n0v, n1v, n2v,
        blk0, blk0 + blk1);
}